// Round 7
// baseline (234.229 us; speedup 1.0000x reference)
//
#include <hip/hip_runtime.h>

#define S_SIGMA 8
#define NBINS   16
#define HDIM    1024
#define WDIM    1024
#define GH      129   // (1024-1)/8 + 2
#define GW      129
#define GZ      17    // NBINS + 1
#define CELLS   (GH*GW*GZ)   // 282897 cells per image
#define ROWSZ   (GW*GZ)      // 2193 float2 per grid row
#define EPSV    1e-8f

// ---- gather splat: one thread per spatial cell, 64-thread blocks ----
// LDS histogram columns are thread-private; atomicAdd -> ds_add_f32 (no
// return) kills the ds_read/add/ds_write RAW chain of the += version.
__global__ __launch_bounds__(64) void splat_gather_kernel(
    const float* __restrict__ img, float* __restrict__ grid, int nImg, int imgBase)
{
    __shared__ float lval[16 * 64];   // [gz][tid] -> bank = tid%32, 2-way free
    __shared__ float lwt [16 * 64];

    int tid = threadIdx.x;
    int idx = blockIdx.x * 64 + tid;
    int total = nImg * GH * GW;
    if (idx >= total) return;

    int b   = idx / (GH * GW);
    int rem = idx - b * (GH * GW);
    int gy  = rem / GW;
    int gx  = rem - gy * GW;

    #pragma unroll
    for (int z = 0; z < 16; ++z) { lval[z * 64 + tid] = 0.f; lwt[z * 64 + tid] = 0.f; }

    const float* ib = img + (size_t)(imgBase + b) * (HDIM * WDIM);

    bool interior = (gx >= 1) & (gx <= 127) & (gy >= 1) & (gy <= 127);
    if (interior) {
        int py = gy & 1, px = gx & 1;
        int ylo = 8 * gy - 4 + py;
        int nr  = 9 - 2 * py;
        int ax  = 8 * gx - 4;           // 4-aligned -> 16B-aligned float4 loads
        #pragma unroll
        for (int r = 0; r < 9; ++r) {
            if (r < nr) {
                const float* rp = ib + (size_t)(ylo + r) * WDIM + ax;
                float4 A = *(const float4*)rp;
                float4 B = *(const float4*)(rp + 4);
                float  cv = rp[8];
                float e7[7] = {A.y, A.z, A.w, B.x, B.y, B.z, B.w};
                #pragma unroll
                for (int j = 0; j < 7; ++j) {
                    float v = e7[j];
                    int gz = min(max((int)rintf(v * 15.0f), 0), 15);
                    atomicAdd(&lval[gz * 64 + tid], v);
                    atomicAdd(&lwt [gz * 64 + tid], 1.0f);
                }
                if (!px) {   // even gx also owns A.x and cv
                    int gz = min(max((int)rintf(A.x * 15.0f), 0), 15);
                    atomicAdd(&lval[gz * 64 + tid], A.x);
                    atomicAdd(&lwt [gz * 64 + tid], 1.0f);
                    gz = min(max((int)rintf(cv * 15.0f), 0), 15);
                    atomicAdd(&lval[gz * 64 + tid], cv);
                    atomicAdd(&lwt [gz * 64 + tid], 1.0f);
                }
            }
        }
    } else {
        int ylo = max(0, 8 * gy - 4 + (gy & 1));
        int yhi = min(HDIM - 1, 8 * gy + 4 - (gy & 1));
        int xlo = max(0, 8 * gx - 4 + (gx & 1));
        int xhi = min(WDIM - 1, 8 * gx + 4 - (gx & 1));
        for (int y = ylo; y <= yhi; ++y) {
            const float* row = ib + (size_t)y * WDIM;
            for (int x = xlo; x <= xhi; ++x) {
                float v = row[x];
                int gz = min(max((int)rintf(v * 15.0f), 0), 15);
                atomicAdd(&lval[gz * 64 + tid], v);
                atomicAdd(&lwt [gz * 64 + tid], 1.0f);
            }
        }
    }

    float2* dst = (float2*)grid + (size_t)idx * GZ;
    #pragma unroll
    for (int z = 0; z < 16; ++z) {
        float2 o; o.x = lval[z * 64 + tid]; o.y = lwt[z * 64 + tid];
        dst[z] = o;
    }
    float2 zero; zero.x = 0.f; zero.y = 0.f;
    dst[16] = zero;
}

// ---- fused y+x+z blur, LDS tiled: 12x12 output cells per block ----
#define TO 12
#define TI 16
#define NIN  (TI*TI*GZ)    // 4352
#define NTMP (TO*TI*GZ)    // 3264
#define NOUT (TO*TO*GZ)    // 2448

__global__ __launch_bounds__(256) void blur_fused_kernel(
    const float2* __restrict__ in, float2* __restrict__ out,
    const float* __restrict__ kfs, const float* __restrict__ kfr)
{
    __shared__ float2 sbin[NIN];
    __shared__ float2 stmp[NTMP];

    int tid = threadIdx.x;
    int tx0 = blockIdx.x * TO;
    int ty0 = blockIdx.y * TO;
    int b   = blockIdx.z;

    float ks[5] = {kfs[0], kfs[1], kfs[2], kfs[3], kfs[4]};
    float kr[5] = {kfr[0], kfr[1], kfr[2], kfr[3], kfr[4]};

    const float2* gb = in + (size_t)b * CELLS;
    for (int li = tid; li < NIN; li += 256) {
        int iy = li / (TI * GZ);
        int r  = li - iy * (TI * GZ);
        int ix = r / GZ;
        int z  = r - ix * GZ;
        int gy = ty0 - 2 + iy;
        int gx = tx0 - 2 + ix;
        float2 v; v.x = 0.f; v.y = 0.f;
        if (gy >= 0 && gy < GH && gx >= 0 && gx < GW)
            v = gb[((size_t)gy * GW + gx) * GZ + z];
        sbin[li] = v;
    }
    __syncthreads();

    for (int o = tid; o < NTMP; o += 256) {
        int oy = o / (TI * GZ);
        int r  = o - oy * (TI * GZ);
        float2 a; a.x = 0.f; a.y = 0.f;
        #pragma unroll
        for (int t = 0; t < 5; ++t) {
            float2 g = sbin[(oy + t) * (TI * GZ) + r];
            a.x += ks[t] * g.x;
            a.y += ks[t] * g.y;
        }
        stmp[o] = a;
    }
    __syncthreads();

    for (int o = tid; o < NOUT; o += 256) {
        int oy = o / (TO * GZ);
        int r  = o - oy * (TO * GZ);
        int ox = r / GZ;
        int z  = r - ox * GZ;
        float2 a; a.x = 0.f; a.y = 0.f;
        #pragma unroll
        for (int t = 0; t < 5; ++t) {
            float2 g = stmp[(oy * TI + ox + t) * GZ + z];
            a.x += ks[t] * g.x;
            a.y += ks[t] * g.y;
        }
        sbin[o] = a;
    }
    __syncthreads();

    float2* ob = out + (size_t)b * CELLS;
    for (int o = tid; o < NOUT; o += 256) {
        int oy = o / (TO * GZ);
        int r  = o - oy * (TO * GZ);
        int ox = r / GZ;
        int z  = r - ox * GZ;
        int gy = ty0 + oy;
        int gx = tx0 + ox;
        if (gy < GH && gx < GW) {
            int base = o - z;
            float2 a; a.x = 0.f; a.y = 0.f;
            #pragma unroll
            for (int t = 0; t < 5; ++t) {
                int zz = z + t - 2;
                if (zz >= 0 && zz < GZ) {
                    float2 g = sbin[base + zz];
                    a.x += kr[t] * g.x;
                    a.y += kr[t] * g.y;
                }
            }
            ob[((size_t)gy * GW + gx) * GZ + z] = a;
        }
    }
}

// ---- slice: natural [r][x0][z] layout, SCALAR val/wt arrays ----
// Staging writes are linear (conflict-free); reads land at bank
// (17*x0v + z0) % 32 where 17*x0v mod 32 is bijective over the wave -> ~free.
__global__ __launch_bounds__(256) void slice_rows_kernel(
    const float* __restrict__ img, const float2* __restrict__ grid,
    float* __restrict__ out, int imgBase)
{
    __shared__ float sval[2 * ROWSZ];   // 4386 floats = 17544 B
    __shared__ float swt [2 * ROWSZ];

    int tid = threadIdx.x;
    int k   = blockIdx.x;    // 0..127 (8-pixel-row group)
    int b   = blockIdx.y;

    const float2* gsrc = grid + (size_t)b * CELLS + (size_t)k * ROWSZ;
    for (int i = tid; i < 2 * ROWSZ; i += 256) {
        float2 g = gsrc[i];
        sval[i] = g.x;
        swt [i] = g.y;
    }
    __syncthreads();

    int x   = tid << 2;          // 4 px per thread per row
    int x0v = tid >> 1;          // x>>3, constant across the quad
    float txb = (float)(x & 7) * 0.125f;
    int xbase = x0v * GZ;

    size_t rowBase = (size_t)(imgBase + b) * (HDIM * WDIM) + (size_t)(k << 3) * WDIM + x;

    #pragma unroll
    for (int r = 0; r < 8; ++r) {
        size_t pixBase = rowBase + (size_t)r * WDIM;
        float4 v4 = *(const float4*)(img + pixBase);
        float ty = (float)r * 0.125f;
        float wy0 = 1.f - ty, wy1 = ty;

        float vv[4] = {v4.x, v4.y, v4.z, v4.w};
        float rr[4];
        #pragma unroll
        for (int j = 0; j < 4; ++j) {
            float v  = vv[j];
            float fz = fminf(fmaxf(v * 15.0f, 0.0f), 15.0f);
            float zf = floorf(fz);
            int   z0 = (int)zf;
            float tz = fz - zf;
            float tx = txb + (float)j * 0.125f;
            float wx0 = 1.f - tx, wx1 = tx;
            float wz0 = 1.f - tz, wz1 = tz;

            int base = xbase + z0;             // row y0; row y1 at +ROWSZ
            float v000 = sval[base];
            float v001 = sval[base + 1];
            float v010 = sval[base + GZ];
            float v011 = sval[base + GZ + 1];
            float v100 = sval[base + ROWSZ];
            float v101 = sval[base + ROWSZ + 1];
            float v110 = sval[base + ROWSZ + GZ];
            float v111 = sval[base + ROWSZ + GZ + 1];
            float w000 = swt[base];
            float w001 = swt[base + 1];
            float w010 = swt[base + GZ];
            float w011 = swt[base + GZ + 1];
            float w100 = swt[base + ROWSZ];
            float w101 = swt[base + ROWSZ + 1];
            float w110 = swt[base + ROWSZ + GZ];
            float w111 = swt[base + ROWSZ + GZ + 1];

            float ov = 0.f, ow = 0.f, w;
            w = wy0 * wx0 * wz0; ov += w * v000; ow += w * w000;
            w = wy0 * wx0 * wz1; ov += w * v001; ow += w * w001;
            w = wy0 * wx1 * wz0; ov += w * v010; ow += w * w010;
            w = wy0 * wx1 * wz1; ov += w * v011; ow += w * w011;
            w = wy1 * wx0 * wz0; ov += w * v100; ow += w * w100;
            w = wy1 * wx0 * wz1; ov += w * v101; ow += w * w101;
            w = wy1 * wx1 * wz0; ov += w * v110; ow += w * w110;
            w = wy1 * wx1 * wz1; ov += w * v111; ow += w * w111;
            rr[j] = ov / (ow + EPSV);
        }
        float4 r4; r4.x = rr[0]; r4.y = rr[1]; r4.z = rr[2]; r4.w = rr[3];
        *(float4*)(out + pixBase) = r4;
    }
}

extern "C" void kernel_launch(void* const* d_in, const int* in_sizes, int n_in,
                              void* d_out, int out_size, void* d_ws, size_t ws_size,
                              hipStream_t stream)
{
    const float* img = (const float*)d_in[0];
    const float* fs  = (const float*)d_in[2];
    const float* fr  = (const float*)d_in[3];
    float* out = (float*)d_out;

    int nImgTotal = in_sizes[0] / (HDIM * WDIM);   // 12
    size_t perImgBytes = (size_t)CELLS * 2 * sizeof(float);

    int maxChunk = (int)(ws_size / (2 * perImgBytes));
    if (maxChunk < 1) return;
    if (maxChunk > nImgTotal) maxChunk = nImgTotal;

    const int tilesPerDim = (GH + TO - 1) / TO;    // 11

    for (int base = 0; base < nImgTotal; base += maxChunk) {
        int c = nImgTotal - base;
        if (c > maxChunk) c = maxChunk;

        float* A = (float*)d_ws;
        float* B = A + (size_t)c * CELLS * 2;

        int nCols = c * GH * GW;
        int colBlocks = (nCols + 63) / 64;
        splat_gather_kernel<<<colBlocks, 64, 0, stream>>>(img, A, c, base);

        dim3 bgrid(tilesPerDim, tilesPerDim, c);
        blur_fused_kernel<<<bgrid, 256, 0, stream>>>((const float2*)A, (float2*)B, fs, fr);

        dim3 sgrid(HDIM / 8, c);
        slice_rows_kernel<<<sgrid, 256, 0, stream>>>(img, (const float2*)B, out, base);
    }
}

// Round 8
// 122.093 us; speedup vs baseline: 1.9184x; 1.9184x over previous
//
#include <hip/hip_runtime.h>

#define S_SIGMA 8
#define NBINS   16
#define HDIM    1024
#define WDIM    1024
#define GH      129   // (1024-1)/8 + 2
#define GW      129
#define GZ      17    // NBINS + 1
#define CELLS   (GH*GW*GZ)   // 282897 cells per image
#define ROWSZ   (GW*GZ)      // 2193 float2 per grid row
#define EPSV    1e-8f

// ---- gather splat: one thread per spatial cell, 64-thread blocks ----
// Two accumulator sets indexed by row parity -> two independent LDS
// read-modify-write chains (ILP). Plain += (NOT atomicAdd: LDS float
// atomics compile to a waited CAS/RTN op - 3.5x slower, round-7 lesson).
__global__ __launch_bounds__(64) void splat_gather_kernel(
    const float* __restrict__ img, float* __restrict__ grid, int nImg, int imgBase)
{
    __shared__ float lval[2 * 16 * 64];   // [set][gz][tid], bank = tid%32
    __shared__ float lwt [2 * 16 * 64];

    int tid = threadIdx.x;
    int idx = blockIdx.x * 64 + tid;
    int total = nImg * GH * GW;
    if (idx >= total) return;

    int b   = idx / (GH * GW);
    int rem = idx - b * (GH * GW);
    int gy  = rem / GW;
    int gx  = rem - gy * GW;

    #pragma unroll
    for (int z = 0; z < 32; ++z) { lval[z * 64 + tid] = 0.f; lwt[z * 64 + tid] = 0.f; }

    const float* ib = img + (size_t)(imgBase + b) * (HDIM * WDIM);

    bool interior = (gx >= 1) & (gx <= 127) & (gy >= 1) & (gy <= 127);
    if (interior) {
        int py = gy & 1, px = gx & 1;
        int ylo = 8 * gy - 4 + py;
        int nr  = 9 - 2 * py;
        int ax  = 8 * gx - 4;           // 4-aligned -> 16B-aligned float4 loads
        #pragma unroll
        for (int r = 0; r < 9; ++r) {
            if (r < nr) {
                const float* rp = ib + (size_t)(ylo + r) * WDIM + ax;
                float4 A = *(const float4*)rp;
                float4 B = *(const float4*)(rp + 4);
                float  cv = rp[8];
                float* sv = lval + (r & 1) * (16 * 64);
                float* sw = lwt  + (r & 1) * (16 * 64);
                float e7[7] = {A.y, A.z, A.w, B.x, B.y, B.z, B.w};
                #pragma unroll
                for (int j = 0; j < 7; ++j) {
                    float v = e7[j];
                    int gz = min(max((int)rintf(v * 15.0f), 0), 15);
                    sv[gz * 64 + tid] += v;
                    sw[gz * 64 + tid] += 1.0f;
                }
                if (!px) {   // even gx also owns A.x and cv
                    int gz = min(max((int)rintf(A.x * 15.0f), 0), 15);
                    sv[gz * 64 + tid] += A.x;
                    sw[gz * 64 + tid] += 1.0f;
                    gz = min(max((int)rintf(cv * 15.0f), 0), 15);
                    sv[gz * 64 + tid] += cv;
                    sw[gz * 64 + tid] += 1.0f;
                }
            }
        }
    } else {
        int ylo = max(0, 8 * gy - 4 + (gy & 1));
        int yhi = min(HDIM - 1, 8 * gy + 4 - (gy & 1));
        int xlo = max(0, 8 * gx - 4 + (gx & 1));
        int xhi = min(WDIM - 1, 8 * gx + 4 - (gx & 1));
        for (int y = ylo; y <= yhi; ++y) {
            const float* row = ib + (size_t)y * WDIM;
            float* sv = lval + (y & 1) * (16 * 64);
            float* sw = lwt  + (y & 1) * (16 * 64);
            for (int x = xlo; x <= xhi; ++x) {
                float v = row[x];
                int gz = min(max((int)rintf(v * 15.0f), 0), 15);
                sv[gz * 64 + tid] += v;
                sw[gz * 64 + tid] += 1.0f;
            }
        }
    }

    float2* dst = (float2*)grid + (size_t)idx * GZ;
    #pragma unroll
    for (int z = 0; z < 16; ++z) {
        float2 o;
        o.x = lval[z * 64 + tid] + lval[(16 + z) * 64 + tid];
        o.y = lwt [z * 64 + tid] + lwt [(16 + z) * 64 + tid];
        dst[z] = o;
    }
    float2 zero; zero.x = 0.f; zero.y = 0.f;
    dst[16] = zero;
}

// ---- fused y+x+z blur, LDS tiled: 12x12 output cells per block ----
#define TO 12
#define TI 16
#define NIN  (TI*TI*GZ)    // 4352
#define NTMP (TO*TI*GZ)    // 3264
#define NOUT (TO*TO*GZ)    // 2448

__global__ __launch_bounds__(256) void blur_fused_kernel(
    const float2* __restrict__ in, float2* __restrict__ out,
    const float* __restrict__ kfs, const float* __restrict__ kfr)
{
    __shared__ float2 sbin[NIN];
    __shared__ float2 stmp[NTMP];

    int tid = threadIdx.x;
    int tx0 = blockIdx.x * TO;
    int ty0 = blockIdx.y * TO;
    int b   = blockIdx.z;

    float ks[5] = {kfs[0], kfs[1], kfs[2], kfs[3], kfs[4]};
    float kr[5] = {kfr[0], kfr[1], kfr[2], kfr[3], kfr[4]};

    const float2* gb = in + (size_t)b * CELLS;
    for (int li = tid; li < NIN; li += 256) {
        int iy = li / (TI * GZ);
        int r  = li - iy * (TI * GZ);
        int ix = r / GZ;
        int z  = r - ix * GZ;
        int gy = ty0 - 2 + iy;
        int gx = tx0 - 2 + ix;
        float2 v; v.x = 0.f; v.y = 0.f;
        if (gy >= 0 && gy < GH && gx >= 0 && gx < GW)
            v = gb[((size_t)gy * GW + gx) * GZ + z];
        sbin[li] = v;
    }
    __syncthreads();

    for (int o = tid; o < NTMP; o += 256) {
        int oy = o / (TI * GZ);
        int r  = o - oy * (TI * GZ);
        float2 a; a.x = 0.f; a.y = 0.f;
        #pragma unroll
        for (int t = 0; t < 5; ++t) {
            float2 g = sbin[(oy + t) * (TI * GZ) + r];
            a.x += ks[t] * g.x;
            a.y += ks[t] * g.y;
        }
        stmp[o] = a;
    }
    __syncthreads();

    for (int o = tid; o < NOUT; o += 256) {
        int oy = o / (TO * GZ);
        int r  = o - oy * (TO * GZ);
        int ox = r / GZ;
        int z  = r - ox * GZ;
        float2 a; a.x = 0.f; a.y = 0.f;
        #pragma unroll
        for (int t = 0; t < 5; ++t) {
            float2 g = stmp[(oy * TI + ox + t) * GZ + z];
            a.x += ks[t] * g.x;
            a.y += ks[t] * g.y;
        }
        sbin[o] = a;
    }
    __syncthreads();

    float2* ob = out + (size_t)b * CELLS;
    for (int o = tid; o < NOUT; o += 256) {
        int oy = o / (TO * GZ);
        int r  = o - oy * (TO * GZ);
        int ox = r / GZ;
        int z  = r - ox * GZ;
        int gy = ty0 + oy;
        int gx = tx0 + ox;
        if (gy < GH && gx < GW) {
            int base = o - z;
            float2 a; a.x = 0.f; a.y = 0.f;
            #pragma unroll
            for (int t = 0; t < 5; ++t) {
                int zz = z + t - 2;
                if (zz >= 0 && zz < GZ) {
                    float2 g = sbin[base + zz];
                    a.x += kr[t] * g.x;
                    a.y += kr[t] * g.y;
                }
            }
            ob[((size_t)gy * GW + gx) * GZ + z] = a;
        }
    }
}

// ---- slice: natural [r][x0][z] layout, SCALAR val/wt arrays ----
// Staging writes are linear (conflict-free); reads land at bank
// (17*x0v + z0) % 32 where 17*x0v mod 32 is bijective over the wave.
__global__ __launch_bounds__(256) void slice_rows_kernel(
    const float* __restrict__ img, const float2* __restrict__ grid,
    float* __restrict__ out, int imgBase)
{
    __shared__ float sval[2 * ROWSZ];   // 4386 floats = 17544 B
    __shared__ float swt [2 * ROWSZ];

    int tid = threadIdx.x;
    int k   = blockIdx.x;    // 0..127 (8-pixel-row group)
    int b   = blockIdx.y;

    const float2* gsrc = grid + (size_t)b * CELLS + (size_t)k * ROWSZ;
    for (int i = tid; i < 2 * ROWSZ; i += 256) {
        float2 g = gsrc[i];
        sval[i] = g.x;
        swt [i] = g.y;
    }
    __syncthreads();

    int x   = tid << 2;          // 4 px per thread per row
    int x0v = tid >> 1;          // x>>3, constant across the quad
    float txb = (float)(x & 7) * 0.125f;
    int xbase = x0v * GZ;

    size_t rowBase = (size_t)(imgBase + b) * (HDIM * WDIM) + (size_t)(k << 3) * WDIM + x;

    #pragma unroll
    for (int r = 0; r < 8; ++r) {
        size_t pixBase = rowBase + (size_t)r * WDIM;
        float4 v4 = *(const float4*)(img + pixBase);
        float ty = (float)r * 0.125f;
        float wy0 = 1.f - ty, wy1 = ty;

        float vv[4] = {v4.x, v4.y, v4.z, v4.w};
        float rr[4];
        #pragma unroll
        for (int j = 0; j < 4; ++j) {
            float v  = vv[j];
            float fz = fminf(fmaxf(v * 15.0f, 0.0f), 15.0f);
            float zf = floorf(fz);
            int   z0 = (int)zf;
            float tz = fz - zf;
            float tx = txb + (float)j * 0.125f;
            float wx0 = 1.f - tx, wx1 = tx;
            float wz0 = 1.f - tz, wz1 = tz;

            int base = xbase + z0;             // row y0; row y1 at +ROWSZ
            float v000 = sval[base];
            float v001 = sval[base + 1];
            float v010 = sval[base + GZ];
            float v011 = sval[base + GZ + 1];
            float v100 = sval[base + ROWSZ];
            float v101 = sval[base + ROWSZ + 1];
            float v110 = sval[base + ROWSZ + GZ];
            float v111 = sval[base + ROWSZ + GZ + 1];
            float w000 = swt[base];
            float w001 = swt[base + 1];
            float w010 = swt[base + GZ];
            float w011 = swt[base + GZ + 1];
            float w100 = swt[base + ROWSZ];
            float w101 = swt[base + ROWSZ + 1];
            float w110 = swt[base + ROWSZ + GZ];
            float w111 = swt[base + ROWSZ + GZ + 1];

            float ov = 0.f, ow = 0.f, w;
            w = wy0 * wx0 * wz0; ov += w * v000; ow += w * w000;
            w = wy0 * wx0 * wz1; ov += w * v001; ow += w * w001;
            w = wy0 * wx1 * wz0; ov += w * v010; ow += w * w010;
            w = wy0 * wx1 * wz1; ov += w * v011; ow += w * w011;
            w = wy1 * wx0 * wz0; ov += w * v100; ow += w * w100;
            w = wy1 * wx0 * wz1; ov += w * v101; ow += w * w101;
            w = wy1 * wx1 * wz0; ov += w * v110; ow += w * w110;
            w = wy1 * wx1 * wz1; ov += w * v111; ow += w * w111;
            rr[j] = ov / (ow + EPSV);
        }
        float4 r4; r4.x = rr[0]; r4.y = rr[1]; r4.z = rr[2]; r4.w = rr[3];
        *(float4*)(out + pixBase) = r4;
    }
}

extern "C" void kernel_launch(void* const* d_in, const int* in_sizes, int n_in,
                              void* d_out, int out_size, void* d_ws, size_t ws_size,
                              hipStream_t stream)
{
    const float* img = (const float*)d_in[0];
    const float* fs  = (const float*)d_in[2];
    const float* fr  = (const float*)d_in[3];
    float* out = (float*)d_out;

    int nImgTotal = in_sizes[0] / (HDIM * WDIM);   // 12
    size_t perImgBytes = (size_t)CELLS * 2 * sizeof(float);

    int maxChunk = (int)(ws_size / (2 * perImgBytes));
    if (maxChunk < 1) return;
    if (maxChunk > nImgTotal) maxChunk = nImgTotal;

    const int tilesPerDim = (GH + TO - 1) / TO;    // 11

    for (int base = 0; base < nImgTotal; base += maxChunk) {
        int c = nImgTotal - base;
        if (c > maxChunk) c = maxChunk;

        float* A = (float*)d_ws;
        float* B = A + (size_t)c * CELLS * 2;

        int nCols = c * GH * GW;
        int colBlocks = (nCols + 63) / 64;
        splat_gather_kernel<<<colBlocks, 64, 0, stream>>>(img, A, c, base);

        dim3 bgrid(tilesPerDim, tilesPerDim, c);
        blur_fused_kernel<<<bgrid, 256, 0, stream>>>((const float2*)A, (float2*)B, fs, fr);

        dim3 sgrid(HDIM / 8, c);
        slice_rows_kernel<<<sgrid, 256, 0, stream>>>(img, (const float2*)B, out, base);
    }
}

// Round 9
// 114.597 us; speedup vs baseline: 2.0439x; 1.0654x over previous
//
#include <hip/hip_runtime.h>

#define S_SIGMA 8
#define NBINS   16
#define HDIM    1024
#define WDIM    1024
#define GH      129   // (1024-1)/8 + 2
#define GW      129
#define GZ      17    // NBINS + 1
#define CELLS   (GH*GW*GZ)   // 282897 cells per image
#define ROWSZ   (GW*GZ)      // 2193 float2 per grid row
#define EPSV    1e-8f

// ---- gather splat: 2 threads per spatial cell (even/odd rows) ----
// 32 cells per 64-thread block; thread t and t+32 own private histogram
// columns for cell (t&31), merged at writeout. Plain += (LDS float
// atomicAdd compiles to waited CAS - 3.5x slower, round-7 lesson).
__global__ __launch_bounds__(64) void splat_gather_kernel(
    const float* __restrict__ img, float* __restrict__ grid, int nImg, int imgBase)
{
    __shared__ float lval[16 * 64];   // [gz][tid], bank = tid%32, 2-way free
    __shared__ float lwt [16 * 64];

    int tid = threadIdx.x;
    int c   = tid & 31;          // cell slot
    int h   = tid >> 5;          // row-parity half
    int cellIdx = blockIdx.x * 32 + c;
    int total = nImg * GH * GW;

    #pragma unroll
    for (int z = 0; z < 16; ++z) { lval[z * 64 + tid] = 0.f; lwt[z * 64 + tid] = 0.f; }

    if (cellIdx < total) {
        int b   = cellIdx / (GH * GW);
        int rem = cellIdx - b * (GH * GW);
        int gy  = rem / GW;
        int gx  = rem - gy * GW;
        const float* ib = img + (size_t)(imgBase + b) * (HDIM * WDIM);

        bool interior = (gx >= 1) & (gx <= 127) & (gy >= 1) & (gy <= 127);
        if (interior) {
            int py = gy & 1, px = gx & 1;
            int ylo = 8 * gy - 4 + py;
            int nr  = 9 - 2 * py;
            int ax  = 8 * gx - 4;           // 4-aligned -> 16B-aligned float4 loads
            #pragma unroll
            for (int r = 0; r < 9; ++r) {
                if (((r & 1) == h) && (r < nr)) {
                    const float* rp = ib + (size_t)(ylo + r) * WDIM + ax;
                    float4 A = *(const float4*)rp;
                    float4 B = *(const float4*)(rp + 4);
                    float  cv = rp[8];
                    float e7[7] = {A.y, A.z, A.w, B.x, B.y, B.z, B.w};
                    #pragma unroll
                    for (int j = 0; j < 7; ++j) {
                        float v = e7[j];
                        int gz = min(max((int)rintf(v * 15.0f), 0), 15);
                        lval[gz * 64 + tid] += v;
                        lwt [gz * 64 + tid] += 1.0f;
                    }
                    if (!px) {   // even gx also owns A.x and cv
                        int gz = min(max((int)rintf(A.x * 15.0f), 0), 15);
                        lval[gz * 64 + tid] += A.x;
                        lwt [gz * 64 + tid] += 1.0f;
                        gz = min(max((int)rintf(cv * 15.0f), 0), 15);
                        lval[gz * 64 + tid] += cv;
                        lwt [gz * 64 + tid] += 1.0f;
                    }
                }
            }
        } else {
            int ylo = max(0, 8 * gy - 4 + (gy & 1));
            int yhi = min(HDIM - 1, 8 * gy + 4 - (gy & 1));
            int xlo = max(0, 8 * gx - 4 + (gx & 1));
            int xhi = min(WDIM - 1, 8 * gx + 4 - (gx & 1));
            for (int y = ylo + h; y <= yhi; y += 2) {
                const float* row = ib + (size_t)y * WDIM;
                for (int x = xlo; x <= xhi; ++x) {
                    float v = row[x];
                    int gz = min(max((int)rintf(v * 15.0f), 0), 15);
                    lval[gz * 64 + tid] += v;
                    lwt [gz * 64 + tid] += 1.0f;
                }
            }
        }
    }
    __syncthreads();

    // merge the two halves; thread h writes z-range [8h, 8h+8)
    if (cellIdx < total) {
        float2* dst = (float2*)grid + (size_t)cellIdx * GZ;
        int zlo = h * 8, zhi = zlo + 8;
        for (int z = zlo; z < zhi; ++z) {
            float2 o;
            o.x = lval[z * 64 + c] + lval[z * 64 + c + 32];
            o.y = lwt [z * 64 + c] + lwt [z * 64 + c + 32];
            dst[z] = o;
        }
        if (h) { float2 zero; zero.x = 0.f; zero.y = 0.f; dst[16] = zero; }
    }
}

// ---- fused y+x+z blur, LDS tiled: 12x12 output cells per block ----
#define TO 12
#define TI 16
#define NIN  (TI*TI*GZ)    // 4352
#define NTMP (TO*TI*GZ)    // 3264
#define NOUT (TO*TO*GZ)    // 2448

__global__ __launch_bounds__(256) void blur_fused_kernel(
    const float2* __restrict__ in, float2* __restrict__ out,
    const float* __restrict__ kfs, const float* __restrict__ kfr)
{
    __shared__ float2 sbin[NIN];
    __shared__ float2 stmp[NTMP];

    int tid = threadIdx.x;
    int tx0 = blockIdx.x * TO;
    int ty0 = blockIdx.y * TO;
    int b   = blockIdx.z;

    float ks[5] = {kfs[0], kfs[1], kfs[2], kfs[3], kfs[4]};
    float kr[5] = {kfr[0], kfr[1], kfr[2], kfr[3], kfr[4]};

    const float2* gb = in + (size_t)b * CELLS;
    for (int li = tid; li < NIN; li += 256) {
        int iy = li / (TI * GZ);
        int r  = li - iy * (TI * GZ);
        int ix = r / GZ;
        int z  = r - ix * GZ;
        int gy = ty0 - 2 + iy;
        int gx = tx0 - 2 + ix;
        float2 v; v.x = 0.f; v.y = 0.f;
        if (gy >= 0 && gy < GH && gx >= 0 && gx < GW)
            v = gb[((size_t)gy * GW + gx) * GZ + z];
        sbin[li] = v;
    }
    __syncthreads();

    for (int o = tid; o < NTMP; o += 256) {
        int oy = o / (TI * GZ);
        int r  = o - oy * (TI * GZ);
        float2 a; a.x = 0.f; a.y = 0.f;
        #pragma unroll
        for (int t = 0; t < 5; ++t) {
            float2 g = sbin[(oy + t) * (TI * GZ) + r];
            a.x += ks[t] * g.x;
            a.y += ks[t] * g.y;
        }
        stmp[o] = a;
    }
    __syncthreads();

    for (int o = tid; o < NOUT; o += 256) {
        int oy = o / (TO * GZ);
        int r  = o - oy * (TO * GZ);
        int ox = r / GZ;
        int z  = r - ox * GZ;
        float2 a; a.x = 0.f; a.y = 0.f;
        #pragma unroll
        for (int t = 0; t < 5; ++t) {
            float2 g = stmp[(oy * TI + ox + t) * GZ + z];
            a.x += ks[t] * g.x;
            a.y += ks[t] * g.y;
        }
        sbin[o] = a;
    }
    __syncthreads();

    float2* ob = out + (size_t)b * CELLS;
    for (int o = tid; o < NOUT; o += 256) {
        int oy = o / (TO * GZ);
        int r  = o - oy * (TO * GZ);
        int ox = r / GZ;
        int z  = r - ox * GZ;
        int gy = ty0 + oy;
        int gx = tx0 + ox;
        if (gy < GH && gx < GW) {
            int base = o - z;
            float2 a; a.x = 0.f; a.y = 0.f;
            #pragma unroll
            for (int t = 0; t < 5; ++t) {
                int zz = z + t - 2;
                if (zz >= 0 && zz < GZ) {
                    float2 g = sbin[base + zz];
                    a.x += kr[t] * g.x;
                    a.y += kr[t] * g.y;
                }
            }
            ob[((size_t)gy * GW + gx) * GZ + z] = a;
        }
    }
}

// ---- slice: float2-interleaved LDS; adjacent z-pair -> ds_read2_b64 ----
// 4 DS instructions per pixel (was 16 scalar reads); random-z0 bank
// collisions are unavoidable but exposure drops 4x.
__global__ __launch_bounds__(256) void slice_rows_kernel(
    const float* __restrict__ img, const float2* __restrict__ grid,
    float* __restrict__ out, int imgBase)
{
    __shared__ float2 sg[2 * ROWSZ];   // rows k,k+1 interleaved (val,wt): 35088 B

    int tid = threadIdx.x;
    int k   = blockIdx.x;    // 0..127 (8-pixel-row group)
    int b   = blockIdx.y;

    const float2* gsrc = grid + (size_t)b * CELLS + (size_t)k * ROWSZ;
    for (int i = tid; i < 2 * ROWSZ; i += 256) sg[i] = gsrc[i];
    __syncthreads();

    int x   = tid << 2;          // 4 px per thread per row
    int x0v = tid >> 1;          // x>>3, constant across the quad
    float txb = (float)(x & 7) * 0.125f;
    int xbase = x0v * GZ;

    size_t rowBase = (size_t)(imgBase + b) * (HDIM * WDIM) + (size_t)(k << 3) * WDIM + x;

    #pragma unroll
    for (int r = 0; r < 8; ++r) {
        size_t pixBase = rowBase + (size_t)r * WDIM;
        float4 v4 = *(const float4*)(img + pixBase);
        float ty = (float)r * 0.125f;
        float wy0 = 1.f - ty, wy1 = ty;

        float vv[4] = {v4.x, v4.y, v4.z, v4.w};
        float rr[4];
        #pragma unroll
        for (int j = 0; j < 4; ++j) {
            float v  = vv[j];
            float fz = fminf(fmaxf(v * 15.0f, 0.0f), 15.0f);
            float zf = floorf(fz);
            int   z0 = (int)zf;
            float tz = fz - zf;
            float tx = txb + (float)j * 0.125f;
            float wx0 = 1.f - tx, wx1 = tx;
            float wz0 = 1.f - tz, wz1 = tz;

            int base = xbase + z0;
            float2 g000 = sg[base];                 // y0 x0 z0
            float2 g001 = sg[base + 1];             // y0 x0 z1
            float2 g010 = sg[base + GZ];            // y0 x1 z0
            float2 g011 = sg[base + GZ + 1];
            float2 g100 = sg[base + ROWSZ];         // y1 x0 z0
            float2 g101 = sg[base + ROWSZ + 1];
            float2 g110 = sg[base + ROWSZ + GZ];
            float2 g111 = sg[base + ROWSZ + GZ + 1];

            float ov = 0.f, ow = 0.f, w;
            w = wy0 * wx0 * wz0; ov += w * g000.x; ow += w * g000.y;
            w = wy0 * wx0 * wz1; ov += w * g001.x; ow += w * g001.y;
            w = wy0 * wx1 * wz0; ov += w * g010.x; ow += w * g010.y;
            w = wy0 * wx1 * wz1; ov += w * g011.x; ow += w * g011.y;
            w = wy1 * wx0 * wz0; ov += w * g100.x; ow += w * g100.y;
            w = wy1 * wx0 * wz1; ov += w * g101.x; ow += w * g101.y;
            w = wy1 * wx1 * wz0; ov += w * g110.x; ow += w * g110.y;
            w = wy1 * wx1 * wz1; ov += w * g111.x; ow += w * g111.y;
            rr[j] = ov / (ow + EPSV);
        }
        float4 r4; r4.x = rr[0]; r4.y = rr[1]; r4.z = rr[2]; r4.w = rr[3];
        *(float4*)(out + pixBase) = r4;
    }
}

extern "C" void kernel_launch(void* const* d_in, const int* in_sizes, int n_in,
                              void* d_out, int out_size, void* d_ws, size_t ws_size,
                              hipStream_t stream)
{
    const float* img = (const float*)d_in[0];
    const float* fs  = (const float*)d_in[2];
    const float* fr  = (const float*)d_in[3];
    float* out = (float*)d_out;

    int nImgTotal = in_sizes[0] / (HDIM * WDIM);   // 12
    size_t perImgBytes = (size_t)CELLS * 2 * sizeof(float);

    int maxChunk = (int)(ws_size / (2 * perImgBytes));
    if (maxChunk < 1) return;
    if (maxChunk > nImgTotal) maxChunk = nImgTotal;

    const int tilesPerDim = (GH + TO - 1) / TO;    // 11

    for (int base = 0; base < nImgTotal; base += maxChunk) {
        int c = nImgTotal - base;
        if (c > maxChunk) c = maxChunk;

        float* A = (float*)d_ws;
        float* B = A + (size_t)c * CELLS * 2;

        int nCells = c * GH * GW;
        int colBlocks = (nCells + 31) / 32;        // 32 cells per 64-thread block
        splat_gather_kernel<<<colBlocks, 64, 0, stream>>>(img, A, c, base);

        dim3 bgrid(tilesPerDim, tilesPerDim, c);
        blur_fused_kernel<<<bgrid, 256, 0, stream>>>((const float2*)A, (float2*)B, fs, fr);

        dim3 sgrid(HDIM / 8, c);
        slice_rows_kernel<<<sgrid, 256, 0, stream>>>(img, (const float2*)B, out, base);
    }
}